// Round 8
// baseline (107.309 us; speedup 1.0000x reference)
//
#include <hip/hip_runtime.h>
#include <math.h>

typedef __attribute__((ext_vector_type(8))) short s16x8;
typedef __attribute__((ext_vector_type(4))) float f32x4;
typedef __attribute__((ext_vector_type(4))) unsigned int u32x4;

#define CCH 128
#define BSZ 32

// fp32 -> bf16 round-to-nearest-even (scalar, for mix kernel)
static __device__ inline unsigned short f2bf(float f) {
    unsigned u = __float_as_uint(f);
    unsigned r = (u + 0x7FFFu + ((u >> 16) & 1u)) >> 16;
    return (unsigned short)r;
}

// packed f32x2 -> bf16x2 (RNE)
static __device__ inline unsigned cvtpk(float lo, float hi) {
    unsigned r;
    asm("v_cvt_pk_bf16_f32 %0, %1, %2" : "=v"(r) : "v"(lo), "v"(hi));
    return r;
}

// ---------------- Kernel A: global average pool ----------------
__global__ __launch_bounds__(256) void pool_kernel(const float* __restrict__ x,
                                                   float* __restrict__ pooled) {
    int blk = blockIdx.x;                 // b*C + c
    const float4* x4 = (const float4*)(x + (size_t)blk * 4096);
    int t = threadIdx.x;
    float s = 0.f;
#pragma unroll
    for (int j = 0; j < 4; ++j) {
        float4 v = x4[j * 256 + t];
        s += v.x + v.y + v.z + v.w;
    }
#pragma unroll
    for (int off = 32; off; off >>= 1) s += __shfl_xor(s, off, 64);
    __shared__ float red[4];
    if ((t & 63) == 0) red[t >> 6] = s;
    __syncthreads();
    if (t == 0) {
        float tot = red[0] + red[1] + red[2] + red[3];
        pooled[blk] = tot * (1.0f / 4096.0f);
    }
}

// ---------------- Kernel B: routing coefficients (once) ----------------
__global__ __launch_bounds__(128) void coeff_kernel(const float* __restrict__ pooled,
                                                    const float* __restrict__ fc_w,
                                                    const float* __restrict__ fc_b,
                                                    float* __restrict__ coeffs) {
    int t = threadIdx.x;
    int b = t >> 2, k = t & 3;
    const float4* p4 = (const float4*)(pooled + b * CCH);
    const float4* w4 = (const float4*)(fc_w + k * CCH);
    float dot = fc_b[k];
#pragma unroll
    for (int j = 0; j < 32; ++j) {
        float4 a = p4[j], w = w4[j];
        dot += a.x * w.x + a.y * w.y + a.z * w.z + a.w * w.w;
    }
    float s = 1.0f / (1.0f + expf(-dot));
    float m = s;
    m = fmaxf(m, __shfl_xor(m, 1, 64));
    m = fmaxf(m, __shfl_xor(m, 2, 64));
    float e = expf(s - m);
    float sum = e;
    sum += __shfl_xor(sum, 1, 64);
    sum += __shfl_xor(sum, 2, 64);
    coeffs[t] = e / sum;
}

// ---------------- Kernel W: mix -> bf16 in conv tile layout ----------------
// wmix per b: [p(12)][dx(3)][wr(2)][mt(4)][lane(64)][8 bf16]  (1024 B tiles)
// Lane l of tile (p,dx,wr,mt): co = wr*64+mt*16+(l&15), ci = (p/3)*32+(l>>4)*8+e,
// tap (dy=p%3, dx) -- exactly the conv A-fragment (1024B coalesced loads there).
__global__ __launch_bounds__(256) void mix_kernel(const float* __restrict__ kernels,
                                                  const float* __restrict__ coeffs,
                                                  unsigned short* __restrict__ wmix) {
    extern __shared__ float klds[];   // 4*4624 = 18496 floats (73984 B)
    int bid = blockIdx.x;
    int bq = bid & 15;
    int rest = bid >> 4;              // 0..31
    int cog = rest & 7, cc = rest >> 3;
    int t = threadIdx.x;

    // ---- stage kernels slice (coalesced: 288-float runs; LDS conflict-free) ----
    const int KSTR = CCH * CCH * 9;
    for (int s = t; s < 4 * 16 * 288; s += 256) {
        int k = s / 4608;
        int rem = s - k * 4608;
        int co = rem / 288;
        int i = rem - co * 288;            // ci*9 + tap
        klds[k * 4624 + co * 289 + i] =
            kernels[(size_t)k * KSTR + ((size_t)(cog * 16 + co) * CCH + cc * 32) * 9 + i];
    }
    __syncthreads();

    int wr = cog >> 2, mt = cog & 3;
#pragma unroll
    for (int jb = 0; jb < 2; ++jb) {
        int b = bq + jb * 16;
        float cf0 = coeffs[b * 4 + 0];
        float cf1 = coeffs[b * 4 + 1];
        float cf2 = coeffs[b * 4 + 2];
        float cf3 = coeffs[b * 4 + 3];
        for (int s = t; s < 576; s += 256) {
            int lane = s & 63;
            int tj = s >> 6;                 // 0..8
            int dy = tj / 3, dx = tj - dy * 3;
            int col = lane & 15;             // co_local
            int ci8 = (lane >> 4) * 8;
            unsigned short vals[8];
#pragma unroll
            for (int e = 0; e < 8; ++e) {
                int idx = col * 289 + (ci8 + e) * 9 + dy * 3 + dx;
                float v = cf0 * klds[idx]
                        + cf1 * klds[4624 + idx]
                        + cf2 * klds[2 * 4624 + idx]
                        + cf3 * klds[3 * 4624 + idx];
                vals[e] = f2bf(v);
            }
            int p = cc * 3 + dy;
            size_t off = (size_t)b * 147456
                       + ((size_t)((p * 3 + dx) * 2 + wr) * 4 + mt) * 512 + (size_t)lane * 8;
            *(s16x8*)&wmix[off] = *(const s16x8*)vals;
        }
    }
}

// ---------------- Kernel C: MFMA implicit-GEMM dynamic conv ----------------
// grid = 512 (32 b x 16 ytiles of 4 rows), 512 threads (8 waves: wr2 x wc4).
// Per block: 128 co x (4 rows x 64 cols); acc[4][4]. Weights consumed as
// registers via coalesced 1024B tile loads (L1/L2-hot, XCD-local).
// xs double-buffered: phase cc issues x(cc+1) loads first (T14), computes 9
// taps from buf[cc&1], packs+writes buf[(cc+1)&1], ONE barrier per phase.
__global__ __launch_bounds__(512, 4) void conv_kernel(const float* __restrict__ x,
                                                      const unsigned short* __restrict__ wmix,
                                                      float* __restrict__ out) {
    __shared__ unsigned short xs[2][6 * 66 * 40];   // 2 x 31680 B

    int bid = blockIdx.x;
    int b = bid & 31, ytile = bid >> 5;             // XCD = b%8 (matches mix writer)
    int y0 = ytile * 4;
    int t = threadIdx.x;
    int l = t & 63, w = t >> 6;
    int wr = w >> 2, wc = w & 3;
    int l15 = l & 15, g = l >> 4;

    const unsigned short* wb = wmix + (size_t)b * 147456;

    // zero halo columns (col 0 and 65), 6 rows, BOTH buffers, once
    if (t < 480) {
        int buf = t / 240;
        int r = t - buf * 240;
        int row = r / 40;
        int colsel = (r / 20) & 1;
        int cpart = r % 20;
        *(unsigned*)&xs[buf][(row * 66 + colsel * 65) * 40 + cpart * 2] = 0u;
    }

    // ---- prologue: stage cc=0 into buf 0 ----
#pragma unroll
    for (int i = 0; i < 3; ++i) {
        int slot = w + i * 8;               // 0..23 = row(6) x colhi(4)
        int row = slot >> 2, colhi = slot & 3;
        int gx = colhi * 16 + l15;
        int gy = y0 + row - 1;
        float v[8];
#pragma unroll
        for (int j = 0; j < 8; ++j) v[j] = 0.f;
        if ((unsigned)gy < 64u) {
            const float* xp = x + (((size_t)b * CCH + g * 8) * 64 + gy) * 64 + gx;
#pragma unroll
            for (int j = 0; j < 8; ++j) v[j] = xp[(size_t)j * 4096];
        }
        unsigned pw[4];
#pragma unroll
        for (int j = 0; j < 4; ++j) pw[j] = cvtpk(v[2 * j], v[2 * j + 1]);
        u32x4 q; q[0] = pw[0]; q[1] = pw[1]; q[2] = pw[2]; q[3] = pw[3];
        *(u32x4*)&xs[0][(size_t)(row * 66 + gx + 1) * 40 + g * 8] = q;
    }
    __syncthreads();

    f32x4 acc[4][4] = {};
    float xv[3][8];

    for (int cc = 0; cc < 4; ++cc) {
        const unsigned short* xcur = xs[cc & 1];
        unsigned short* xnxt = xs[(cc + 1) & 1];

        // ---- T14: issue x(cc+1) loads now; consumed after the tap loop ----
        if (cc < 3) {
#pragma unroll
            for (int i = 0; i < 3; ++i) {
                int slot = w + i * 8;
                int row = slot >> 2, colhi = slot & 3;
                int gx = colhi * 16 + l15;
                int gy = y0 + row - 1;
#pragma unroll
                for (int j = 0; j < 8; ++j) xv[i][j] = 0.f;
                if ((unsigned)gy < 64u) {
                    const float* xp = x + (((size_t)b * CCH + (cc + 1) * 32 + g * 8) * 64 + gy) * 64 + gx;
#pragma unroll
                    for (int j = 0; j < 8; ++j) xv[i][j] = xp[(size_t)j * 4096];
                }
            }
        }

        // ---- compute: 3 dy x 3 dx, A from global (coalesced, L1-hot), B from LDS ----
#pragma unroll
        for (int dy = 0; dy < 3; ++dy) {
            int p = cc * 3 + dy;
            int xrow = wc + dy;
#pragma unroll
            for (int dx = 0; dx < 3; ++dx) {
                const unsigned short* wt = wb + ((size_t)((p * 3 + dx) * 2 + wr) * 4) * 512
                                              + (size_t)l * 8;
                s16x8 a[4];
#pragma unroll
                for (int mt = 0; mt < 4; ++mt)
                    a[mt] = *(const s16x8*)(wt + mt * 512);
#pragma unroll
                for (int nt = 0; nt < 4; ++nt) {
                    s16x8 bf = *(const s16x8*)&xcur[(size_t)(xrow * 66 + nt * 16 + l15 + dx) * 40 + g * 8];
#pragma unroll
                    for (int mt = 0; mt < 4; ++mt)
                        acc[mt][nt] = __builtin_amdgcn_mfma_f32_16x16x32_bf16(
                            a[mt], bf, acc[mt][nt], 0, 0, 0);
                }
            }
        }

        // ---- pack + publish x(cc+1) into the other buffer ----
        if (cc < 3) {
#pragma unroll
            for (int i = 0; i < 3; ++i) {
                int slot = w + i * 8;
                int row = slot >> 2, colhi = slot & 3;
                int gx = colhi * 16 + l15;
                unsigned pw[4];
#pragma unroll
                for (int j = 0; j < 4; ++j) pw[j] = cvtpk(xv[i][2 * j], xv[i][2 * j + 1]);
                u32x4 q; q[0] = pw[0]; q[1] = pw[1]; q[2] = pw[2]; q[3] = pw[3];
                *(u32x4*)&xnxt[(size_t)(row * 66 + gx + 1) * 40 + g * 8] = q;
            }
        }
        __syncthreads();   // buf[(cc+1)&1] ready; buf[cc&1] reads quiesced
    }

    // ---- epilogue ----
    int gy = y0 + wc;
#pragma unroll
    for (int mt = 0; mt < 4; ++mt)
#pragma unroll
        for (int nt = 0; nt < 4; ++nt) {
            int gxo = nt * 16 + l15;
#pragma unroll
            for (int j = 0; j < 4; ++j) {
                int co = wr * 64 + mt * 16 + g * 4 + j;
                out[(((size_t)b * CCH + co) * 64 + gy) * 64 + gxo] = acc[mt][nt][j];
            }
        }
}

extern "C" void kernel_launch(void* const* d_in, const int* in_sizes, int n_in,
                              void* d_out, int out_size, void* d_ws, size_t ws_size,
                              hipStream_t stream) {
    const float* x       = (const float*)d_in[0];   // [32,128,64,64]
    const float* kernels = (const float*)d_in[1];   // [4,128,128,3,3]
    const float* fc_w    = (const float*)d_in[2];   // [4,128]
    const float* fc_b    = (const float*)d_in[3];   // [4]
    float* out = (float*)d_out;

    float* pooled = (float*)d_ws;                                   // 4096 f
    float* coeffs = pooled + BSZ * CCH;                             // 128 f
    unsigned short* wmix = (unsigned short*)((char*)d_ws + 32768);  // 9.4 MB bf16

    hipFuncSetAttribute((const void*)mix_kernel,
                        hipFuncAttributeMaxDynamicSharedMemorySize, 73984);

    pool_kernel<<<BSZ * CCH, 256, 0, stream>>>(x, pooled);
    coeff_kernel<<<1, 128, 0, stream>>>(pooled, fc_w, fc_b, coeffs);
    mix_kernel<<<512, 256, 73984, stream>>>(kernels, coeffs, wmix);
    conv_kernel<<<512, 512, 0, stream>>>(x, wmix, out);
}

// Round 9
// 91.671 us; speedup vs baseline: 1.1706x; 1.1706x over previous
//
#include <hip/hip_runtime.h>
#include <math.h>

typedef __attribute__((ext_vector_type(8))) short s16x8;
typedef __attribute__((ext_vector_type(4))) float f32x4;
typedef __attribute__((ext_vector_type(4))) unsigned int u32x4;
typedef __attribute__((ext_vector_type(2))) unsigned int u32x2;

#define CCH 128
#define BSZ 32

// fp32 -> bf16 round-to-nearest-even (scalar, for mix kernel)
static __device__ inline unsigned short f2bf(float f) {
    unsigned u = __float_as_uint(f);
    unsigned r = (u + 0x7FFFu + ((u >> 16) & 1u)) >> 16;
    return (unsigned short)r;
}

// packed f32x2 -> bf16x2 (RNE)
static __device__ inline unsigned cvtpk(float lo, float hi) {
    unsigned r;
    asm("v_cvt_pk_bf16_f32 %0, %1, %2" : "=v"(r) : "v"(lo), "v"(hi));
    return r;
}

// ---------------- Kernel A: global average pool ----------------
__global__ __launch_bounds__(256) void pool_kernel(const float* __restrict__ x,
                                                   float* __restrict__ pooled) {
    int blk = blockIdx.x;                 // b*C + c
    const float4* x4 = (const float4*)(x + (size_t)blk * 4096);
    int t = threadIdx.x;
    float s = 0.f;
#pragma unroll
    for (int j = 0; j < 4; ++j) {
        float4 v = x4[j * 256 + t];
        s += v.x + v.y + v.z + v.w;
    }
#pragma unroll
    for (int off = 32; off; off >>= 1) s += __shfl_xor(s, off, 64);
    __shared__ float red[4];
    if ((t & 63) == 0) red[t >> 6] = s;
    __syncthreads();
    if (t == 0) {
        float tot = red[0] + red[1] + red[2] + red[3];
        pooled[blk] = tot * (1.0f / 4096.0f);
    }
}

// ---------------- Kernel B: routing coefficients (once) ----------------
__global__ __launch_bounds__(128) void coeff_kernel(const float* __restrict__ pooled,
                                                    const float* __restrict__ fc_w,
                                                    const float* __restrict__ fc_b,
                                                    float* __restrict__ coeffs) {
    int t = threadIdx.x;
    int b = t >> 2, k = t & 3;
    const float4* p4 = (const float4*)(pooled + b * CCH);
    const float4* w4 = (const float4*)(fc_w + k * CCH);
    float dot = fc_b[k];
#pragma unroll
    for (int j = 0; j < 32; ++j) {
        float4 a = p4[j], w = w4[j];
        dot += a.x * w.x + a.y * w.y + a.z * w.z + a.w * w.w;
    }
    float s = 1.0f / (1.0f + expf(-dot));
    float m = s;
    m = fmaxf(m, __shfl_xor(m, 1, 64));
    m = fmaxf(m, __shfl_xor(m, 2, 64));
    float e = expf(s - m);
    float sum = e;
    sum += __shfl_xor(sum, 1, 64);
    sum += __shfl_xor(sum, 2, 64);
    coeffs[t] = e / sum;
}

// ---------------- Kernel W: mix -> bf16 in conv tile layout ----------------
// wmix per b: [p(12)][dx(3)][wr(2)][mt(4)][lane(64)][8 bf16]  (1024 B tiles)
// Lane l of tile (p,dx,wr,mt): co = wr*64+mt*16+(l&15), ci = (p/3)*32+(l>>4)*8+e,
// tap (dy=p%3, dx) -- exactly the conv A-fragment (1024B coalesced loads there).
__global__ __launch_bounds__(256) void mix_kernel(const float* __restrict__ kernels,
                                                  const float* __restrict__ coeffs,
                                                  unsigned short* __restrict__ wmix) {
    extern __shared__ float klds[];   // 4*4624 = 18496 floats (73984 B)
    int bid = blockIdx.x;
    int bq = bid & 15;
    int rest = bid >> 4;              // 0..31
    int cog = rest & 7, cc = rest >> 3;
    int t = threadIdx.x;

    // ---- stage kernels slice (coalesced: 288-float runs; LDS conflict-free) ----
    const int KSTR = CCH * CCH * 9;
    for (int s = t; s < 4 * 16 * 288; s += 256) {
        int k = s / 4608;
        int rem = s - k * 4608;
        int co = rem / 288;
        int i = rem - co * 288;            // ci*9 + tap
        klds[k * 4624 + co * 289 + i] =
            kernels[(size_t)k * KSTR + ((size_t)(cog * 16 + co) * CCH + cc * 32) * 9 + i];
    }
    __syncthreads();

    int wr = cog >> 2, mt = cog & 3;
#pragma unroll
    for (int jb = 0; jb < 2; ++jb) {
        int b = bq + jb * 16;
        float cf0 = coeffs[b * 4 + 0];
        float cf1 = coeffs[b * 4 + 1];
        float cf2 = coeffs[b * 4 + 2];
        float cf3 = coeffs[b * 4 + 3];
        for (int s = t; s < 576; s += 256) {
            int lane = s & 63;
            int tj = s >> 6;                 // 0..8
            int dy = tj / 3, dx = tj - dy * 3;
            int col = lane & 15;             // co_local
            int ci8 = (lane >> 4) * 8;
            unsigned short vals[8];
#pragma unroll
            for (int e = 0; e < 8; ++e) {
                int idx = col * 289 + (ci8 + e) * 9 + dy * 3 + dx;
                float v = cf0 * klds[idx]
                        + cf1 * klds[4624 + idx]
                        + cf2 * klds[2 * 4624 + idx]
                        + cf3 * klds[3 * 4624 + idx];
                vals[e] = f2bf(v);
            }
            int p = cc * 3 + dy;
            size_t off = (size_t)b * 147456
                       + ((size_t)((p * 3 + dx) * 2 + wr) * 4 + mt) * 512 + (size_t)lane * 8;
            *(s16x8*)&wmix[off] = *(const s16x8*)vals;
        }
    }
}

// ---------------- Kernel C: MFMA implicit-GEMM dynamic conv ----------------
// grid = 512 (32 b x 16 ytiles of 4 rows), 1024 threads (16 waves: wr2 x wc4 x wn2).
// Per block: 128 co x (4 rows x 64 cols); per-wave acc[4][2] = 32 AGPR ->
// ~90 free VGPRs at __launch_bounds__(1024,4) fund T14 x-prefetch + 1-tap-ahead
// A prefetch. xs double-buffered, ONE barrier per cc phase.
__global__ __launch_bounds__(1024, 4) void conv_kernel(const float* __restrict__ x,
                                                       const unsigned short* __restrict__ wmix,
                                                       float* __restrict__ out) {
    __shared__ unsigned short xs[2][6 * 66 * 40];   // 2 x 31680 B

    int bid = blockIdx.x;
    int b = bid & 31, ytile = bid >> 5;             // XCD = b%8 (matches mix writer)
    int y0 = ytile * 4;
    int t = threadIdx.x;
    int l = t & 63, w = t >> 6;                     // 16 waves
    int wr = w >> 3, wc = (w >> 1) & 3, wn = w & 1;
    int l15 = l & 15, g = l >> 4;

    const unsigned short* wb = wmix + (size_t)b * 147456;

    // zero halo columns (col 0 and 65), 6 rows, BOTH buffers, once
    if (t < 480) {
        int buf = t / 240;
        int r = t - buf * 240;
        int row = r / 40;
        int colsel = (r / 20) & 1;
        int cpart = r % 20;
        *(unsigned*)&xs[buf][(row * 66 + colsel * 65) * 40 + cpart * 2] = 0u;
    }

    // staging: 3072 half-tasks (4 ci each) -> 3 per thread, balanced.
    // half-task h: slot = h>>7 (row=slot>>2, colhi=slot&3), r7 = h&127:
    //   gx = colhi*16 + (r7&15), oct g = (r7>>4)&3, half = (r7>>6)&1
    int hrow[3], hgx[3], hg[3], hh[3];
#pragma unroll
    for (int k = 0; k < 3; ++k) {
        int h = t + k * 1024;
        int slot = h >> 7, r7 = h & 127;
        hrow[k] = slot >> 2;
        hgx[k] = (slot & 3) * 16 + (r7 & 15);
        hg[k] = (r7 >> 4) & 3;
        hh[k] = (r7 >> 6) & 1;
    }

    // ---- prologue: stage cc=0 into buf 0 ----
#pragma unroll
    for (int k = 0; k < 3; ++k) {
        int gy = y0 + hrow[k] - 1;
        float v0 = 0.f, v1 = 0.f, v2 = 0.f, v3 = 0.f;
        if ((unsigned)gy < 64u) {
            const float* xp = x + (((size_t)b * CCH + hg[k] * 8 + hh[k] * 4) * 64 + gy) * 64 + hgx[k];
            v0 = xp[0]; v1 = xp[4096]; v2 = xp[2 * 4096]; v3 = xp[3 * 4096];
        }
        u32x2 q; q[0] = cvtpk(v0, v1); q[1] = cvtpk(v2, v3);
        *(u32x2*)&xs[0][(size_t)(hrow[k] * 66 + hgx[k] + 1) * 40 + hg[k] * 8 + hh[k] * 4] = q;
    }
    __syncthreads();

    f32x4 acc[4][2] = {};
    float xv[3][4];

    for (int cc = 0; cc < 4; ++cc) {
        const unsigned short* xcur = xs[cc & 1];
        unsigned short* xnxt = xs[(cc + 1) & 1];

        // ---- T14: issue x(cc+1) loads first; consumed after the tap loop ----
        if (cc < 3) {
#pragma unroll
            for (int k = 0; k < 3; ++k) {
                int gy = y0 + hrow[k] - 1;
                xv[k][0] = 0.f; xv[k][1] = 0.f; xv[k][2] = 0.f; xv[k][3] = 0.f;
                if ((unsigned)gy < 64u) {
                    const float* xp = x + (((size_t)b * CCH + (cc + 1) * 32 + hg[k] * 8 + hh[k] * 4) * 64 + gy) * 64 + hgx[k];
                    xv[k][0] = xp[0]; xv[k][1] = xp[4096];
                    xv[k][2] = xp[2 * 4096]; xv[k][3] = xp[3 * 4096];
                }
            }
        }

        // ---- compute: 9 taps, A pipelined one tap ahead ----
        s16x8 a[4], an[4];
        {
            const unsigned short* wt = wb + ((size_t)((cc * 3) * 3 * 2 + wr) * 4) * 512 + (size_t)l * 8;
#pragma unroll
            for (int mt = 0; mt < 4; ++mt) a[mt] = *(const s16x8*)(wt + mt * 512);
        }
#pragma unroll
        for (int tap = 0; tap < 9; ++tap) {
            int dy = tap / 3, dx = tap - dy * 3;
            if (tap < 8) {
                int tap2 = tap + 1;
                int dy2 = tap2 / 3, dx2 = tap2 - dy2 * 3;
                const unsigned short* wt2 = wb + ((size_t)(((cc * 3 + dy2) * 3 + dx2) * 2 + wr) * 4) * 512
                                               + (size_t)l * 8;
#pragma unroll
                for (int mt = 0; mt < 4; ++mt) an[mt] = *(const s16x8*)(wt2 + mt * 512);
            }
            int xrow = wc + dy;
            int cb = wn * 32 + dx;
            s16x8 b0 = *(const s16x8*)&xcur[(size_t)(xrow * 66 + cb + l15) * 40 + g * 8];
            s16x8 b1 = *(const s16x8*)&xcur[(size_t)(xrow * 66 + cb + 16 + l15) * 40 + g * 8];
#pragma unroll
            for (int mt = 0; mt < 4; ++mt) {
                acc[mt][0] = __builtin_amdgcn_mfma_f32_16x16x32_bf16(a[mt], b0, acc[mt][0], 0, 0, 0);
                acc[mt][1] = __builtin_amdgcn_mfma_f32_16x16x32_bf16(a[mt], b1, acc[mt][1], 0, 0, 0);
            }
            if (tap < 8) {
#pragma unroll
                for (int mt = 0; mt < 4; ++mt) a[mt] = an[mt];
            }
        }

        // ---- pack + publish x(cc+1) into the other buffer (no extra barrier) ----
        if (cc < 3) {
#pragma unroll
            for (int k = 0; k < 3; ++k) {
                u32x2 q; q[0] = cvtpk(xv[k][0], xv[k][1]); q[1] = cvtpk(xv[k][2], xv[k][3]);
                *(u32x2*)&xnxt[(size_t)(hrow[k] * 66 + hgx[k] + 1) * 40 + hg[k] * 8 + hh[k] * 4] = q;
            }
        }
        __syncthreads();   // buf[(cc+1)&1] ready; buf[cc&1] reads quiesced
    }

    // ---- epilogue ----
    int gy = y0 + wc;
#pragma unroll
    for (int mt = 0; mt < 4; ++mt)
#pragma unroll
        for (int ntl = 0; ntl < 2; ++ntl) {
            int gxo = (wn * 2 + ntl) * 16 + l15;
#pragma unroll
            for (int j = 0; j < 4; ++j) {
                int co = wr * 64 + mt * 16 + g * 4 + j;
                out[(((size_t)b * CCH + co) * 64 + gy) * 64 + gxo] = acc[mt][ntl][j];
            }
        }
}

extern "C" void kernel_launch(void* const* d_in, const int* in_sizes, int n_in,
                              void* d_out, int out_size, void* d_ws, size_t ws_size,
                              hipStream_t stream) {
    const float* x       = (const float*)d_in[0];   // [32,128,64,64]
    const float* kernels = (const float*)d_in[1];   // [4,128,128,3,3]
    const float* fc_w    = (const float*)d_in[2];   // [4,128]
    const float* fc_b    = (const float*)d_in[3];   // [4]
    float* out = (float*)d_out;

    float* pooled = (float*)d_ws;                                   // 4096 f
    float* coeffs = pooled + BSZ * CCH;                             // 128 f
    unsigned short* wmix = (unsigned short*)((char*)d_ws + 32768);  // 9.4 MB bf16

    hipFuncSetAttribute((const void*)mix_kernel,
                        hipFuncAttributeMaxDynamicSharedMemorySize, 73984);

    pool_kernel<<<BSZ * CCH, 256, 0, stream>>>(x, pooled);
    coeff_kernel<<<1, 128, 0, stream>>>(pooled, fc_w, fc_b, coeffs);
    mix_kernel<<<512, 256, 73984, stream>>>(kernels, coeffs, wmix);
    conv_kernel<<<512, 1024, 0, stream>>>(x, wmix, out);
}